// Round 15
// baseline (61.395 us; speedup 1.0000x reference)
//
#include <hip/hip_runtime.h>
#include <math.h>

// Problem constants (match reference)
static constexpr int BN = 8;      // batch
static constexpr int TS = 2048;   // sequence length
static constexpr int CE = 1024;   // embed dim
static constexpr int HD = 64;     // head size

typedef __attribute__((ext_vector_type(8))) short bf16x8;
typedef __attribute__((ext_vector_type(4))) float f32x4;

typedef __attribute__((address_space(3))) void lds_void;
typedef __attribute__((address_space(1))) void glb_void;

__device__ __forceinline__ unsigned short f2bf(float f) {
    union { float f; unsigned u; } v; v.f = f;
    unsigned r = v.u + 0x7FFF + ((v.u >> 16) & 1);   // round-to-nearest-even
    return (unsigned short)(r >> 16);
}

// 8 f32 -> 8 bf16 via v_cvt_pk_bf16_f32 (RNE, 4 instructions)
__device__ __forceinline__ bf16x8 pack8(const float4& a, const float4& b) {
    union { unsigned u[4]; bf16x8 v; } r;
    asm("v_cvt_pk_bf16_f32 %0, %1, %2" : "=v"(r.u[0]) : "v"(a.x), "v"(a.y));
    asm("v_cvt_pk_bf16_f32 %0, %1, %2" : "=v"(r.u[1]) : "v"(a.z), "v"(a.w));
    asm("v_cvt_pk_bf16_f32 %0, %1, %2" : "=v"(r.u[2]) : "v"(b.x), "v"(b.y));
    asm("v_cvt_pk_bf16_f32 %0, %1, %2" : "=v"(r.u[3]) : "v"(b.z), "v"(b.w));
    return r.v;
}

// ---------------------------------------------------------------------------
// Kernel 0: W transpose + bf16 convert.  Wt[n][k] (n in 0..191 = q|k|v).
//   NEW: Wq scaled by 0.125 (1/sqrt(HD)) here — exact in bf16 (exponent
//   shift), so attention's softmax path drops 32 v_mul per tile.
// ---------------------------------------------------------------------------
__global__ __launch_bounds__(256) void wt_kernel(
    const float* __restrict__ Wq, const float* __restrict__ Wk,
    const float* __restrict__ Wv, unsigned short* __restrict__ Wt)
{
    __shared__ float T[64 * 69];
    const int tid = threadIdx.x;
    const int m  = blockIdx.x >> 4;   // 0..2
    const int kt = blockIdx.x & 15;   // 0..15
    const float* W = (m == 0) ? Wq : (m == 1) ? Wk : Wv;
    const float scale = (m == 0) ? 0.125f : 1.0f;
    const int k0 = kt * 64;

    #pragma unroll
    for (int it = 0; it < 4; ++it) {
        int idx = tid + it * 256;
        int r = idx >> 4, nq = idx & 15;
        float4 v = *(const float4*)(W + (long)(k0 + r) * HD + nq * 4);
        T[r * 69 + nq * 4 + 0] = v.x * scale;
        T[r * 69 + nq * 4 + 1] = v.y * scale;
        T[r * 69 + nq * 4 + 2] = v.z * scale;
        T[r * 69 + nq * 4 + 3] = v.w * scale;
    }
    __syncthreads();
    #pragma unroll
    for (int it = 0; it < 2; ++it) {
        int idx = tid + it * 256;
        int n = idx >> 3, kq = idx & 7;
        unsigned short h[8];
        #pragma unroll
        for (int s = 0; s < 8; ++s)
            h[s] = f2bf(T[(kq * 8 + s) * 69 + n]);
        *(uint4*)(Wt + (long)(m * 64 + n) * CE + k0 + kq * 8) = *(uint4*)h;
    }
}

// ---------------------------------------------------------------------------
// Kernel 1: QKV projection (bf16 MFMA GEMM), Mtile=64 gll ring pipeline.
//   R8-exact (best known: ~32 us).
// ---------------------------------------------------------------------------
static constexpr int NTI = CE / 64;  // 16 K-steps of 64

__global__ __launch_bounds__(512, 1) void qkv_mfma_kernel(
    const float* __restrict__ x, const unsigned short* __restrict__ Wt,
    unsigned short* __restrict__ qo, unsigned short* __restrict__ ko,
    unsigned short* __restrict__ vo)
{
    __shared__ __align__(16) float          xR[3][64 * 64];    // 3 x 16 KB
    __shared__ __align__(16) unsigned short wR[3][192 * 64];   // 3 x 24 KB

    const int tid = threadIdx.x;
    const int l  = tid & 63;
    const int v  = tid >> 6;          // wave 0..7
    const int lr = l & 15, h = l >> 4;
    const int wr = v >> 2;            // row-group 0..1  (32 rows each)
    const int wc = v & 3;             // col-group 0..3  (48 cols each)
    const long row0 = (long)blockIdx.x * 64;

    const float* xsrc0; const float* xsrc1;
    {
        int G, r_, gd;
        G = tid;        r_ = G >> 4; gd = G & 15;
        xsrc0 = x + (row0 + r_) * CE + (gd ^ (r_ & 15)) * 4;
        G = 512 + tid;  r_ = G >> 4; gd = G & 15;
        xsrc1 = x + (row0 + r_) * CE + (gd ^ (r_ & 15)) * 4;
    }
    const int xd0 = 256 * v;
    const int xd1 = 2048 + 256 * v;

    const unsigned short* wsrc0; const unsigned short* wsrc1;
    const unsigned short* wsrc2;
    {
        int G, rw, g8;
        G = tid;         rw = G >> 3; g8 = G & 7;
        wsrc0 = Wt + (long)rw * CE + (g8 ^ (rw & 7)) * 8;
        G = 512 + tid;   rw = G >> 3; g8 = G & 7;
        wsrc1 = Wt + (long)rw * CE + (g8 ^ (rw & 7)) * 8;
        G = 1024 + tid;  rw = G >> 3; g8 = G & 7;
        wsrc2 = Wt + (long)rw * CE + (g8 ^ (rw & 7)) * 8;
    }
    const int wd0 = 512 * v;
    const int wd1 = 4096 + 512 * v;
    const int wd2 = 8192 + 512 * v;

    f32x4 acc[2][3];
    #pragma unroll
    for (int i = 0; i < 2; ++i)
        #pragma unroll
        for (int j = 0; j < 3; ++j)
            acc[i][j] = (f32x4){0.f, 0.f, 0.f, 0.f};

    #define STAGE(nb, t) do {                                                 \
        __builtin_amdgcn_global_load_lds((const glb_void*)(xsrc0 + (t) * 64), \
            (lds_void*)(&xR[nb][xd0]), 16, 0, 0);                             \
        __builtin_amdgcn_global_load_lds((const glb_void*)(xsrc1 + (t) * 64), \
            (lds_void*)(&xR[nb][xd1]), 16, 0, 0);                             \
        __builtin_amdgcn_global_load_lds((const glb_void*)(wsrc0 + (t) * 64), \
            (lds_void*)(&wR[nb][wd0]), 16, 0, 0);                             \
        __builtin_amdgcn_global_load_lds((const glb_void*)(wsrc1 + (t) * 64), \
            (lds_void*)(&wR[nb][wd1]), 16, 0, 0);                             \
        __builtin_amdgcn_global_load_lds((const glb_void*)(wsrc2 + (t) * 64), \
            (lds_void*)(&wR[nb][wd2]), 16, 0, 0);                             \
        __builtin_amdgcn_sched_barrier(0); } while (0)

    #define COMPUTE(cb) do {                                                  \
        _Pragma("unroll")                                                     \
        for (int kk = 0; kk < 2; ++kk) {                                      \
            const int g0 = kk * 8 + 2 * h;                                    \
            bf16x8 af[2];                                                     \
            _Pragma("unroll")                                                 \
            for (int i = 0; i < 2; ++i) {                                     \
                const int rowi = 32 * wr + 16 * i + lr;                       \
                float4 a0 = *(const float4*)(&xR[cb][rowi * 64 + ((g0    ) ^ lr) * 4]); \
                float4 a1 = *(const float4*)(&xR[cb][rowi * 64 + ((g0 + 1) ^ lr) * 4]); \
                af[i] = pack8(a0, a1);                                        \
            }                                                                 \
            _Pragma("unroll")                                                 \
            for (int j = 0; j < 3; ++j) {                                     \
                const int roww = 48 * wc + 16 * j + lr;                       \
                const int gw = (kk * 4 + h) ^ (lr & 7);                       \
                bf16x8 bf = *(const bf16x8*)(&wR[cb][roww * 64 + gw * 8]);    \
                _Pragma("unroll")                                             \
                for (int i = 0; i < 2; ++i)                                   \
                    acc[i][j] = __builtin_amdgcn_mfma_f32_16x16x32_bf16(      \
                        af[i], bf, acc[i][j], 0, 0, 0);                       \
            }                                                                 \
        } } while (0)

    STAGE(0, 0);
    STAGE(1, 1);
    STAGE(2, 2);

    #pragma unroll
    for (int t = 0; t < NTI; ++t) {
        const int cb = t % 3;
        if      (t <= NTI - 3) asm volatile("s_waitcnt vmcnt(10)" ::: "memory");
        else if (t == NTI - 2) asm volatile("s_waitcnt vmcnt(5)"  ::: "memory");
        else                   asm volatile("s_waitcnt vmcnt(0)"  ::: "memory");
        __builtin_amdgcn_s_barrier();
        asm volatile("" ::: "memory");
        COMPUTE(cb);
        __builtin_amdgcn_s_barrier();   // all waves done reading cb
        if (t + 3 < NTI) STAGE(cb, t + 3);
    }
    #undef STAGE
    #undef COMPUTE

    // ---- epilogue.  C/D: col = lane&15, row = 4*(lane>>4)+reg.
    #pragma unroll
    for (int j = 0; j < 3; ++j) {
        const int n0 = 48 * wc + 16 * j;
        if (n0 < 128) {
            unsigned short* outp = (n0 < 64) ? qo : ko;
            const int h0 = (n0 & 63) + lr;
            #pragma unroll
            for (int i = 0; i < 2; ++i)
                #pragma unroll
                for (int r = 0; r < 4; ++r) {
                    long rowg = row0 + 32 * wr + 16 * i + h * 4 + r;
                    outp[rowg * HD + h0] = f2bf(acc[i][j][r]);
                }
        } else {
            const int d  = (n0 - 128) + lr;
            const int bb = (int)(row0 >> 11);
            #pragma unroll
            for (int i = 0; i < 2; ++i) {
                const int t0 = (int)(row0 & 2047) + 32 * wr + 16 * i + h * 4;
                unsigned short h4[4];
                #pragma unroll
                for (int r = 0; r < 4; ++r) h4[r] = f2bf(acc[i][j][r]);
                *(uint2*)(vo + (((long)(bb * 64 + d)) << 11) + t0) = *(uint2*)h4;
            }
        }
    }
}

// ---------------------------------------------------------------------------
// Kernel 2: causal flash attention, bf16 MFMA.
//   8 waves, split-K 8-way; paired (qt, 63-qt) halves.
//   NEW: K/V register DOUBLE-BUFFER prefetch — tile t+8's 16 fragment loads
//   issue (sched_barrier-pinned) before tile t's softmax/PV, hiding L2
//   latency under compute.  Static reg sets A/B (no runtime indexing).
//   Q pre-scaled by 0.125 at wt-time -> no scale mul in softmax.
// ---------------------------------------------------------------------------
__global__ __launch_bounds__(512, 2) void attn_mfma_kernel(
    const unsigned short* __restrict__ qg,
    const unsigned short* __restrict__ kg,
    const unsigned short* __restrict__ vtg,
    float* __restrict__ out)
{
    __shared__ unsigned short Pl[8][32 * 72];   // per-wave P (bf16), 36.9 KB
    __shared__ float Ow[8][32 * 64];            // partial O, 64 KB
    __shared__ float Ml[8][32], Ll[8][32];      // 2 KB

    const int tid = threadIdx.x;
    const int w  = tid >> 6;        // 0..7
    const int l  = tid & 63;
    const int lr = l & 15, h = l >> 4;
    const int b  = blockIdx.x & 7;          // XCD-pinned batch
    const int pr = (blockIdx.x >> 3) & 31;

    const unsigned short* qB = qg  + (long)b * TS * HD;
    const unsigned short* kB = kg  + (long)b * TS * HD;
    const unsigned short* vT = vtg + (long)b * HD * TS;
    float* outB = out + (long)b * TS * HD;

    unsigned short* Pw = &Pl[w][0];

    for (int half = 0; half < 2; ++half) {
        const int qt = half ? (63 - pr) : pr;
        const int q0 = qt * 32;
        const int NT = (qt + 2) >> 1;   // KV tiles of 64 keys

        bf16x8 Qf[2][2];
        #pragma unroll
        for (int qf = 0; qf < 2; ++qf)
            #pragma unroll
            for (int ks = 0; ks < 2; ++ks)
                Qf[qf][ks] = *(const bf16x8*)(qB + (q0 + 16 * qf + lr) * HD + 32 * ks + 8 * h);

        f32x4 O[2][4];
        #pragma unroll
        for (int rf = 0; rf < 2; ++rf)
            #pragma unroll
            for (int cf = 0; cf < 4; ++cf)
                O[rf][cf] = (f32x4){0.f, 0.f, 0.f, 0.f};
        float mrow[2] = {-1e30f, -1e30f};
        float lrow[2] = {0.f, 0.f};

        bf16x8 KA[4][2], VA[4][2], KB_[4][2], VB_[4][2];

        auto loadkv = [&](bf16x8 (&Kf)[4][2], bf16x8 (&Vf)[4][2], int kt) {
            const int key0 = kt * 64;
            #pragma unroll
            for (int kf = 0; kf < 4; ++kf)
                #pragma unroll
                for (int ks = 0; ks < 2; ++ks)
                    Kf[kf][ks] = *(const bf16x8*)(kB + (key0 + 16 * kf + lr) * HD + 32 * ks + 8 * h);
            #pragma unroll
            for (int cf = 0; cf < 4; ++cf)
                #pragma unroll
                for (int ks = 0; ks < 2; ++ks)
                    Vf[cf][ks] = *(const bf16x8*)(vT + (16 * cf + lr) * TS + key0 + 32 * ks + 8 * h);
            __builtin_amdgcn_sched_barrier(0);
        };

        auto process = [&](bf16x8 (&Kf)[4][2], bf16x8 (&Vf)[4][2], int kt) {
            const int key0 = kt * 64;
            f32x4 st[4][2];
            #pragma unroll
            for (int kf = 0; kf < 4; ++kf)
                #pragma unroll
                for (int qf = 0; qf < 2; ++qf)
                    st[kf][qf] = (f32x4){0.f, 0.f, 0.f, 0.f};
            #pragma unroll
            for (int ks = 0; ks < 2; ++ks)
                #pragma unroll
                for (int kf = 0; kf < 4; ++kf)
                    #pragma unroll
                    for (int qf = 0; qf < 2; ++qf)
                        st[kf][qf] = __builtin_amdgcn_mfma_f32_16x16x32_bf16(
                            Kf[kf][ks], Qf[qf][ks], st[kf][qf], 0, 0, 0);

            const bool lastt = (kt == NT - 1);
            float alpha[2];
            #pragma unroll
            for (int qf = 0; qf < 2; ++qf) {
                const int qrow = q0 + 16 * qf + lr;
                float tm = -1e30f;
                #pragma unroll
                for (int kf = 0; kf < 4; ++kf)
                    #pragma unroll
                    for (int r = 0; r < 4; ++r) {
                        float sv = st[kf][qf][r];     // scale folded into Wq
                        if (lastt && (key0 + 16 * kf + 4 * h + r) > qrow) sv = -1e30f;
                        st[kf][qf][r] = sv;
                        tm = fmaxf(tm, sv);
                    }
                tm = fmaxf(tm, __shfl_xor(tm, 16));
                tm = fmaxf(tm, __shfl_xor(tm, 32));
                const float mn = fmaxf(mrow[qf], tm);
                alpha[qf] = __expf(mrow[qf] - mn);
                mrow[qf] = mn;
                float rs = 0.f;
                #pragma unroll
                for (int kf = 0; kf < 4; ++kf)
                    #pragma unroll
                    for (int r = 0; r < 4; ++r) {
                        float pv = __expf(st[kf][qf][r] - mn);
                        st[kf][qf][r] = pv;
                        rs += pv;
                    }
                rs += __shfl_xor(rs, 16);
                rs += __shfl_xor(rs, 32);
                lrow[qf] = lrow[qf] * alpha[qf] + rs;
                #pragma unroll
                for (int kf = 0; kf < 4; ++kf) {
                    unsigned a01 = (unsigned)f2bf(st[kf][qf][0]) |
                                   ((unsigned)f2bf(st[kf][qf][1]) << 16);
                    unsigned a23 = (unsigned)f2bf(st[kf][qf][2]) |
                                   ((unsigned)f2bf(st[kf][qf][3]) << 16);
                    unsigned short* pp = Pw + (16 * qf + lr) * 72 + 16 * kf + 4 * h;
                    *(unsigned*)(pp)     = a01;
                    *(unsigned*)(pp + 2) = a23;
                }
            }

            #pragma unroll
            for (int rf = 0; rf < 2; ++rf)
                #pragma unroll
                for (int r = 0; r < 4; ++r) {
                    float aO = __shfl(alpha[rf], 4 * h + r);
                    #pragma unroll
                    for (int cf = 0; cf < 4; ++cf)
                        O[rf][cf][r] *= aO;
                }

            bf16x8 pa[2][2];
            #pragma unroll
            for (int rf = 0; rf < 2; ++rf)
                #pragma unroll
                for (int ks = 0; ks < 2; ++ks)
                    pa[rf][ks] = *(const bf16x8*)(Pw + (16 * rf + lr) * 72 + 32 * ks + 8 * h);
            #pragma unroll
            for (int ks = 0; ks < 2; ++ks)
                #pragma unroll
                for (int rf = 0; rf < 2; ++rf)
                    #pragma unroll
                    for (int cf = 0; cf < 4; ++cf)
                        O[rf][cf] = __builtin_amdgcn_mfma_f32_16x16x32_bf16(
                            pa[rf][ks], Vf[cf][ks], O[rf][cf], 0, 0, 0);
        };

        // ---- software-pipelined split-K loop (2 tiles per iteration)
        if (w < NT) loadkv(KA, VA, w);
        for (int kt = w; kt < NT; kt += 16) {
            const int ktB = kt + 8;
            if (ktB < NT) loadkv(KB_, VB_, ktB);     // prefetch under process(A)
            process(KA, VA, kt);
            if (ktB < NT) {
                if (kt + 16 < NT) loadkv(KA, VA, kt + 16);  // prefetch under B
                process(KB_, VB_, ktB);
            }
        }

        // ---- write this wave's partials
        #pragma unroll
        for (int rf = 0; rf < 2; ++rf)
            #pragma unroll
            for (int cf = 0; cf < 4; ++cf)
                #pragma unroll
                for (int r = 0; r < 4; ++r)
                    Ow[w][(16 * rf + 4 * h + r) * 64 + 16 * cf + lr] = O[rf][cf][r];
        if (h == 0) {
            #pragma unroll
            for (int qf = 0; qf < 2; ++qf) {
                Ml[w][16 * qf + lr] = mrow[qf];
                Ll[w][16 * qf + lr] = lrow[qf];
            }
        }
        __syncthreads();

        // ---- merge 8 partials: thread -> (q = tid>>4, d0 = (tid&15)*4)
        {
            const int q  = tid >> 4;
            const int d0 = (tid & 15) * 4;
            float mM = -1e30f;
            #pragma unroll
            for (int w2 = 0; w2 < 8; ++w2) mM = fmaxf(mM, Ml[w2][q]);
            float lS = 0.f;
            float a4[4] = {0.f, 0.f, 0.f, 0.f};
            #pragma unroll
            for (int w2 = 0; w2 < 8; ++w2) {
                float sc = __expf(Ml[w2][q] - mM);
                lS += Ll[w2][q] * sc;
                float4 ov = *(const float4*)(&Ow[w2][q * 64 + d0]);
                a4[0] += sc * ov.x; a4[1] += sc * ov.y;
                a4[2] += sc * ov.z; a4[3] += sc * ov.w;
            }
            const float inv = 1.f / lS;
            float4 o1 = {a4[0]*inv, a4[1]*inv, a4[2]*inv, a4[3]*inv};
            *(float4*)(outB + (long)(q0 + q) * HD + d0) = o1;
        }
        __syncthreads();
    }
}

// ---------------------------------------------------------------------------
extern "C" void kernel_launch(void* const* d_in, const int* in_sizes, int n_in,
                              void* d_out, int out_size, void* d_ws, size_t ws_size,
                              hipStream_t stream) {
    const float* x  = (const float*)d_in[0];
    const float* Wq = (const float*)d_in[1];
    const float* Wk = (const float*)d_in[2];
    const float* Wv = (const float*)d_in[3];
    float* out = (float*)d_out;

    const size_t nqkv = (size_t)BN * TS * HD;   // 1,048,576 elems
    unsigned short* qb = (unsigned short*)d_ws;          // 2 MB bf16 [b*t][d]
    unsigned short* kb = qb + nqkv;                      // 2 MB bf16 [b*t][d]
    unsigned short* vt = kb + nqkv;                      // 2 MB bf16 [b][d][t]

    // Wt (bf16, 384 KB) in d_out scratch; consumed before attn overwrites.
    unsigned short* Wt = (unsigned short*)d_out;

    wt_kernel<<<48, 256, 0, stream>>>(Wq, Wk, Wv, Wt);
    qkv_mfma_kernel<<<(BN * TS) / 64, 512, 0, stream>>>(x, Wt, qb, kb, vt);
    attn_mfma_kernel<<<BN * 32, 512, 0, stream>>>(qb, kb, vt, out);
}

// Round 16
// 50.096 us; speedup vs baseline: 1.2255x; 1.2255x over previous
//
#include <hip/hip_runtime.h>
#include <math.h>

// Problem constants (match reference)
static constexpr int BN = 8;      // batch
static constexpr int TS = 2048;   // sequence length
static constexpr int CE = 1024;   // embed dim
static constexpr int HD = 64;     // head size

typedef __attribute__((ext_vector_type(8))) short bf16x8;
typedef __attribute__((ext_vector_type(4))) float f32x4;

typedef __attribute__((address_space(3))) void lds_void;
typedef __attribute__((address_space(1))) void glb_void;

__device__ __forceinline__ unsigned short f2bf(float f) {
    union { float f; unsigned u; } v; v.f = f;
    unsigned r = v.u + 0x7FFF + ((v.u >> 16) & 1);   // round-to-nearest-even
    return (unsigned short)(r >> 16);
}

// 8 f32 -> 8 bf16 via v_cvt_pk_bf16_f32 (RNE, 4 instructions)
__device__ __forceinline__ bf16x8 pack8(const float4& a, const float4& b) {
    union { unsigned u[4]; bf16x8 v; } r;
    asm("v_cvt_pk_bf16_f32 %0, %1, %2" : "=v"(r.u[0]) : "v"(a.x), "v"(a.y));
    asm("v_cvt_pk_bf16_f32 %0, %1, %2" : "=v"(r.u[1]) : "v"(a.z), "v"(a.w));
    asm("v_cvt_pk_bf16_f32 %0, %1, %2" : "=v"(r.u[2]) : "v"(b.x), "v"(b.y));
    asm("v_cvt_pk_bf16_f32 %0, %1, %2" : "=v"(r.u[3]) : "v"(b.z), "v"(b.w));
    return r.v;
}

// ---------------------------------------------------------------------------
// Kernel 0: W transpose + bf16 convert.  Wt[n][k] (n in 0..191 = q|k|v).
//   Wq scaled by 0.125 (1/sqrt(HD)) here — exact in bf16 (exponent shift).
// ---------------------------------------------------------------------------
__global__ __launch_bounds__(256) void wt_kernel(
    const float* __restrict__ Wq, const float* __restrict__ Wk,
    const float* __restrict__ Wv, unsigned short* __restrict__ Wt)
{
    __shared__ float T[64 * 69];
    const int tid = threadIdx.x;
    const int m  = blockIdx.x >> 4;   // 0..2
    const int kt = blockIdx.x & 15;   // 0..15
    const float* W = (m == 0) ? Wq : (m == 1) ? Wk : Wv;
    const float scale = (m == 0) ? 0.125f : 1.0f;
    const int k0 = kt * 64;

    #pragma unroll
    for (int it = 0; it < 4; ++it) {
        int idx = tid + it * 256;
        int r = idx >> 4, nq = idx & 15;
        float4 v = *(const float4*)(W + (long)(k0 + r) * HD + nq * 4);
        T[r * 69 + nq * 4 + 0] = v.x * scale;
        T[r * 69 + nq * 4 + 1] = v.y * scale;
        T[r * 69 + nq * 4 + 2] = v.z * scale;
        T[r * 69 + nq * 4 + 3] = v.w * scale;
    }
    __syncthreads();
    #pragma unroll
    for (int it = 0; it < 2; ++it) {
        int idx = tid + it * 256;
        int n = idx >> 3, kq = idx & 7;
        unsigned short h[8];
        #pragma unroll
        for (int s = 0; s < 8; ++s)
            h[s] = f2bf(T[(kq * 8 + s) * 69 + n]);
        *(uint4*)(Wt + (long)(m * 64 + n) * CE + k0 + kq * 8) = *(uint4*)h;
    }
}

// ---------------------------------------------------------------------------
// Kernel 1: QKV projection (bf16 MFMA GEMM), Mtile=64 gll pipeline.
//   CHANGE vs R8: ring-2 (80 KB LDS) -> 2 blocks/CU co-resident, doubling
//   per-CU memory-level parallelism.  Steady-state wait vmcnt(5) (stage t+1
//   in flight); stage(t+2) issued post-compute into the freed buffer.
// ---------------------------------------------------------------------------
static constexpr int NTI = CE / 64;  // 16 K-steps of 64

__global__ __launch_bounds__(512, 1) void qkv_mfma_kernel(
    const float* __restrict__ x, const unsigned short* __restrict__ Wt,
    unsigned short* __restrict__ qo, unsigned short* __restrict__ ko,
    unsigned short* __restrict__ vo)
{
    __shared__ __align__(16) float          xR[2][64 * 64];    // 2 x 16 KB
    __shared__ __align__(16) unsigned short wR[2][192 * 64];   // 2 x 24 KB

    const int tid = threadIdx.x;
    const int l  = tid & 63;
    const int v  = tid >> 6;          // wave 0..7
    const int lr = l & 15, h = l >> 4;
    const int wr = v >> 2;            // row-group 0..1  (32 rows each)
    const int wc = v & 3;             // col-group 0..3  (48 cols each)
    const long row0 = (long)blockIdx.x * 64;

    const float* xsrc0; const float* xsrc1;
    {
        int G, r_, gd;
        G = tid;        r_ = G >> 4; gd = G & 15;
        xsrc0 = x + (row0 + r_) * CE + (gd ^ (r_ & 15)) * 4;
        G = 512 + tid;  r_ = G >> 4; gd = G & 15;
        xsrc1 = x + (row0 + r_) * CE + (gd ^ (r_ & 15)) * 4;
    }
    const int xd0 = 256 * v;
    const int xd1 = 2048 + 256 * v;

    const unsigned short* wsrc0; const unsigned short* wsrc1;
    const unsigned short* wsrc2;
    {
        int G, rw, g8;
        G = tid;         rw = G >> 3; g8 = G & 7;
        wsrc0 = Wt + (long)rw * CE + (g8 ^ (rw & 7)) * 8;
        G = 512 + tid;   rw = G >> 3; g8 = G & 7;
        wsrc1 = Wt + (long)rw * CE + (g8 ^ (rw & 7)) * 8;
        G = 1024 + tid;  rw = G >> 3; g8 = G & 7;
        wsrc2 = Wt + (long)rw * CE + (g8 ^ (rw & 7)) * 8;
    }
    const int wd0 = 512 * v;
    const int wd1 = 4096 + 512 * v;
    const int wd2 = 8192 + 512 * v;

    f32x4 acc[2][3];
    #pragma unroll
    for (int i = 0; i < 2; ++i)
        #pragma unroll
        for (int j = 0; j < 3; ++j)
            acc[i][j] = (f32x4){0.f, 0.f, 0.f, 0.f};

    #define STAGE(nb, t) do {                                                 \
        __builtin_amdgcn_global_load_lds((const glb_void*)(xsrc0 + (t) * 64), \
            (lds_void*)(&xR[nb][xd0]), 16, 0, 0);                             \
        __builtin_amdgcn_global_load_lds((const glb_void*)(xsrc1 + (t) * 64), \
            (lds_void*)(&xR[nb][xd1]), 16, 0, 0);                             \
        __builtin_amdgcn_global_load_lds((const glb_void*)(wsrc0 + (t) * 64), \
            (lds_void*)(&wR[nb][wd0]), 16, 0, 0);                             \
        __builtin_amdgcn_global_load_lds((const glb_void*)(wsrc1 + (t) * 64), \
            (lds_void*)(&wR[nb][wd1]), 16, 0, 0);                             \
        __builtin_amdgcn_global_load_lds((const glb_void*)(wsrc2 + (t) * 64), \
            (lds_void*)(&wR[nb][wd2]), 16, 0, 0);                             \
        __builtin_amdgcn_sched_barrier(0); } while (0)

    #define COMPUTE(cb) do {                                                  \
        _Pragma("unroll")                                                     \
        for (int kk = 0; kk < 2; ++kk) {                                      \
            const int g0 = kk * 8 + 2 * h;                                    \
            bf16x8 af[2];                                                     \
            _Pragma("unroll")                                                 \
            for (int i = 0; i < 2; ++i) {                                     \
                const int rowi = 32 * wr + 16 * i + lr;                       \
                float4 a0 = *(const float4*)(&xR[cb][rowi * 64 + ((g0    ) ^ lr) * 4]); \
                float4 a1 = *(const float4*)(&xR[cb][rowi * 64 + ((g0 + 1) ^ lr) * 4]); \
                af[i] = pack8(a0, a1);                                        \
            }                                                                 \
            _Pragma("unroll")                                                 \
            for (int j = 0; j < 3; ++j) {                                     \
                const int roww = 48 * wc + 16 * j + lr;                       \
                const int gw = (kk * 4 + h) ^ (lr & 7);                       \
                bf16x8 bf = *(const bf16x8*)(&wR[cb][roww * 64 + gw * 8]);    \
                _Pragma("unroll")                                             \
                for (int i = 0; i < 2; ++i)                                   \
                    acc[i][j] = __builtin_amdgcn_mfma_f32_16x16x32_bf16(      \
                        af[i], bf, acc[i][j], 0, 0, 0);                       \
            }                                                                 \
        } } while (0)

    // ---- prologue: fill both buffers (10 glls outstanding)
    STAGE(0, 0);
    STAGE(1, 1);

    #pragma unroll
    for (int t = 0; t < NTI; ++t) {
        const int cb = t & 1;
        // wait for stage t; stage t+1 (5 glls) stays in flight
        if (t <= NTI - 2) asm volatile("s_waitcnt vmcnt(5)" ::: "memory");
        else              asm volatile("s_waitcnt vmcnt(0)" ::: "memory");
        __builtin_amdgcn_s_barrier();
        asm volatile("" ::: "memory");
        COMPUTE(cb);
        __builtin_amdgcn_s_barrier();   // all waves done reading cb
        if (t + 2 < NTI) STAGE(cb, t + 2);
    }
    #undef STAGE
    #undef COMPUTE

    // ---- epilogue.  C/D: col = lane&15, row = 4*(lane>>4)+reg.
    #pragma unroll
    for (int j = 0; j < 3; ++j) {
        const int n0 = 48 * wc + 16 * j;
        if (n0 < 128) {
            unsigned short* outp = (n0 < 64) ? qo : ko;
            const int h0 = (n0 & 63) + lr;
            #pragma unroll
            for (int i = 0; i < 2; ++i)
                #pragma unroll
                for (int r = 0; r < 4; ++r) {
                    long rowg = row0 + 32 * wr + 16 * i + h * 4 + r;
                    outp[rowg * HD + h0] = f2bf(acc[i][j][r]);
                }
        } else {
            const int d  = (n0 - 128) + lr;
            const int bb = (int)(row0 >> 11);
            #pragma unroll
            for (int i = 0; i < 2; ++i) {
                const int t0 = (int)(row0 & 2047) + 32 * wr + 16 * i + h * 4;
                unsigned short h4[4];
                #pragma unroll
                for (int r = 0; r < 4; ++r) h4[r] = f2bf(acc[i][j][r]);
                *(uint2*)(vo + (((long)(bb * 64 + d)) << 11) + t0) = *(uint2*)h4;
            }
        }
    }
}

// ---------------------------------------------------------------------------
// Kernel 2: causal flash attention, bf16 MFMA — R14-measured version
// (8 waves, split-K 8-way, no prefetch, no min-wave bound).  Only diff:
// scale folded into Wq upstream, so no *0.125 here.
// ---------------------------------------------------------------------------
__global__ __launch_bounds__(512) void attn_mfma_kernel(
    const unsigned short* __restrict__ qg,
    const unsigned short* __restrict__ kg,
    const unsigned short* __restrict__ vtg,
    float* __restrict__ out)
{
    __shared__ unsigned short Pl[8][32 * 72];   // per-wave P (bf16), 36.9 KB
    __shared__ float Ow[8][32 * 64];            // partial O, 64 KB
    __shared__ float Ml[8][32], Ll[8][32];      // 2 KB

    const int tid = threadIdx.x;
    const int w  = tid >> 6;        // 0..7
    const int l  = tid & 63;
    const int lr = l & 15, h = l >> 4;
    const int b  = blockIdx.x & 7;          // XCD-pinned batch
    const int pr = (blockIdx.x >> 3) & 31;

    const unsigned short* qB = qg  + (long)b * TS * HD;
    const unsigned short* kB = kg  + (long)b * TS * HD;
    const unsigned short* vT = vtg + (long)b * HD * TS;
    float* outB = out + (long)b * TS * HD;

    unsigned short* Pw = &Pl[w][0];

    for (int half = 0; half < 2; ++half) {
        const int qt = half ? (63 - pr) : pr;
        const int q0 = qt * 32;
        const int NT = (qt + 2) >> 1;   // KV tiles of 64 keys

        bf16x8 Qf[2][2];
        #pragma unroll
        for (int qf = 0; qf < 2; ++qf)
            #pragma unroll
            for (int ks = 0; ks < 2; ++ks)
                Qf[qf][ks] = *(const bf16x8*)(qB + (q0 + 16 * qf + lr) * HD + 32 * ks + 8 * h);

        f32x4 O[2][4];
        #pragma unroll
        for (int rf = 0; rf < 2; ++rf)
            #pragma unroll
            for (int cf = 0; cf < 4; ++cf)
                O[rf][cf] = (f32x4){0.f, 0.f, 0.f, 0.f};
        float mrow[2] = {-1e30f, -1e30f};
        float lrow[2] = {0.f, 0.f};

        for (int kt = w; kt < NT; kt += 8) {
            const int key0 = kt * 64;
            bf16x8 Kf[4][2], Vf[4][2];
            #pragma unroll
            for (int kf = 0; kf < 4; ++kf)
                #pragma unroll
                for (int ks = 0; ks < 2; ++ks)
                    Kf[kf][ks] = *(const bf16x8*)(kB + (key0 + 16 * kf + lr) * HD + 32 * ks + 8 * h);
            #pragma unroll
            for (int cf = 0; cf < 4; ++cf)
                #pragma unroll
                for (int ks = 0; ks < 2; ++ks)
                    Vf[cf][ks] = *(const bf16x8*)(vT + (16 * cf + lr) * TS + key0 + 32 * ks + 8 * h);

            f32x4 st[4][2];
            #pragma unroll
            for (int kf = 0; kf < 4; ++kf)
                #pragma unroll
                for (int qf = 0; qf < 2; ++qf)
                    st[kf][qf] = (f32x4){0.f, 0.f, 0.f, 0.f};
            #pragma unroll
            for (int ks = 0; ks < 2; ++ks)
                #pragma unroll
                for (int kf = 0; kf < 4; ++kf)
                    #pragma unroll
                    for (int qf = 0; qf < 2; ++qf)
                        st[kf][qf] = __builtin_amdgcn_mfma_f32_16x16x32_bf16(
                            Kf[kf][ks], Qf[qf][ks], st[kf][qf], 0, 0, 0);

            const bool lastt = (kt == NT - 1);
            float alpha[2];
            #pragma unroll
            for (int qf = 0; qf < 2; ++qf) {
                const int qrow = q0 + 16 * qf + lr;
                float tm = -1e30f;
                #pragma unroll
                for (int kf = 0; kf < 4; ++kf)
                    #pragma unroll
                    for (int r = 0; r < 4; ++r) {
                        float sv = st[kf][qf][r];     // scale folded into Wq
                        if (lastt && (key0 + 16 * kf + 4 * h + r) > qrow) sv = -1e30f;
                        st[kf][qf][r] = sv;
                        tm = fmaxf(tm, sv);
                    }
                tm = fmaxf(tm, __shfl_xor(tm, 16));
                tm = fmaxf(tm, __shfl_xor(tm, 32));
                const float mn = fmaxf(mrow[qf], tm);
                alpha[qf] = __expf(mrow[qf] - mn);
                mrow[qf] = mn;
                float rs = 0.f;
                #pragma unroll
                for (int kf = 0; kf < 4; ++kf)
                    #pragma unroll
                    for (int r = 0; r < 4; ++r) {
                        float pv = __expf(st[kf][qf][r] - mn);
                        st[kf][qf][r] = pv;
                        rs += pv;
                    }
                rs += __shfl_xor(rs, 16);
                rs += __shfl_xor(rs, 32);
                lrow[qf] = lrow[qf] * alpha[qf] + rs;
                #pragma unroll
                for (int kf = 0; kf < 4; ++kf) {
                    unsigned a01 = (unsigned)f2bf(st[kf][qf][0]) |
                                   ((unsigned)f2bf(st[kf][qf][1]) << 16);
                    unsigned a23 = (unsigned)f2bf(st[kf][qf][2]) |
                                   ((unsigned)f2bf(st[kf][qf][3]) << 16);
                    unsigned short* pp = Pw + (16 * qf + lr) * 72 + 16 * kf + 4 * h;
                    *(unsigned*)(pp)     = a01;
                    *(unsigned*)(pp + 2) = a23;
                }
            }

            #pragma unroll
            for (int rf = 0; rf < 2; ++rf)
                #pragma unroll
                for (int r = 0; r < 4; ++r) {
                    float aO = __shfl(alpha[rf], 4 * h + r);
                    #pragma unroll
                    for (int cf = 0; cf < 4; ++cf)
                        O[rf][cf][r] *= aO;
                }

            bf16x8 pa[2][2];
            #pragma unroll
            for (int rf = 0; rf < 2; ++rf)
                #pragma unroll
                for (int ks = 0; ks < 2; ++ks)
                    pa[rf][ks] = *(const bf16x8*)(Pw + (16 * rf + lr) * 72 + 32 * ks + 8 * h);
            #pragma unroll
            for (int ks = 0; ks < 2; ++ks)
                #pragma unroll
                for (int rf = 0; rf < 2; ++rf)
                    #pragma unroll
                    for (int cf = 0; cf < 4; ++cf)
                        O[rf][cf] = __builtin_amdgcn_mfma_f32_16x16x32_bf16(
                            pa[rf][ks], Vf[cf][ks], O[rf][cf], 0, 0, 0);
        }

        // ---- write this wave's partials
        #pragma unroll
        for (int rf = 0; rf < 2; ++rf)
            #pragma unroll
            for (int cf = 0; cf < 4; ++cf)
                #pragma unroll
                for (int r = 0; r < 4; ++r)
                    Ow[w][(16 * rf + 4 * h + r) * 64 + 16 * cf + lr] = O[rf][cf][r];
        if (h == 0) {
            #pragma unroll
            for (int qf = 0; qf < 2; ++qf) {
                Ml[w][16 * qf + lr] = mrow[qf];
                Ll[w][16 * qf + lr] = lrow[qf];
            }
        }
        __syncthreads();

        // ---- merge 8 partials: thread -> (q = tid>>4, d0 = (tid&15)*4)
        {
            const int q  = tid >> 4;
            const int d0 = (tid & 15) * 4;
            float mM = -1e30f;
            #pragma unroll
            for (int w2 = 0; w2 < 8; ++w2) mM = fmaxf(mM, Ml[w2][q]);
            float lS = 0.f;
            float a4[4] = {0.f, 0.f, 0.f, 0.f};
            #pragma unroll
            for (int w2 = 0; w2 < 8; ++w2) {
                float sc = __expf(Ml[w2][q] - mM);
                lS += Ll[w2][q] * sc;
                float4 ov = *(const float4*)(&Ow[w2][q * 64 + d0]);
                a4[0] += sc * ov.x; a4[1] += sc * ov.y;
                a4[2] += sc * ov.z; a4[3] += sc * ov.w;
            }
            const float inv = 1.f / lS;
            float4 o1 = {a4[0]*inv, a4[1]*inv, a4[2]*inv, a4[3]*inv};
            *(float4*)(outB + (long)(q0 + q) * HD + d0) = o1;
        }
        __syncthreads();
    }
}

// ---------------------------------------------------------------------------
extern "C" void kernel_launch(void* const* d_in, const int* in_sizes, int n_in,
                              void* d_out, int out_size, void* d_ws, size_t ws_size,
                              hipStream_t stream) {
    const float* x  = (const float*)d_in[0];
    const float* Wq = (const float*)d_in[1];
    const float* Wk = (const float*)d_in[2];
    const float* Wv = (const float*)d_in[3];
    float* out = (float*)d_out;

    const size_t nqkv = (size_t)BN * TS * HD;   // 1,048,576 elems
    unsigned short* qb = (unsigned short*)d_ws;          // 2 MB bf16 [b*t][d]
    unsigned short* kb = qb + nqkv;                      // 2 MB bf16 [b*t][d]
    unsigned short* vt = kb + nqkv;                      // 2 MB bf16 [b][d][t]

    // Wt (bf16, 384 KB) in d_out scratch; consumed before attn overwrites.
    unsigned short* Wt = (unsigned short*)d_out;

    wt_kernel<<<48, 256, 0, stream>>>(Wq, Wk, Wv, Wt);
    qkv_mfma_kernel<<<(BN * TS) / 64, 512, 0, stream>>>(x, Wt, qb, kb, vt);
    attn_mfma_kernel<<<BN * 32, 512, 0, stream>>>(qb, kb, vt, out);
}